// Round 3
// baseline (310.454 us; speedup 1.0000x reference)
//
#include <hip/hip_runtime.h>

// GestureRNN v11: producer/consumer layer split across 2 waves + DPP gather.
// B=4096, T=512, IN=10, H=32, NCLS=9.
//
// v10 post-mortem: pinning weights changed nothing (215.7 vs 215.0 us,
// VALUBusy 82->82) => no remat existed; weights already resident. The ~1030
// cyc/step is dominated by per-wave stall (VALUBusy 82% is consistent with
// 4 independent ~33%-busy SIMDs: 1-0.67^4 = 0.80) with only 1 wave/SIMD to
// hide the serial recurrence chain. v11 exploits "layer0 never reads layer1":
// wave A runs the h1 recurrence (gather + 32 fdot2 + xproj) and streams h1[t]
// into a double-buffered LDS ring; wave B lags one 16-step chunk, consuming
// h1[t] (natural-order LDS read, no DPP, unpermuted W_ih1) and running the h2
// recurrence (gather h2 + 64 fdot2). 2048 waves => 2 waves/SIMD; stalls of one
// wave are covered by the other. Chunk sync = raw s_barrier with LGKMCNT-ONLY
// drains (asm sandwich) so A's global x prefetch is never drained (v8 lesson).
// Ring parity: A writes buf ph&1 in phase ph; B reads buf (ph-1)&1 -> disjoint
// within a phase, one barrier separates A's overwrite from B's read.

constexpr int T_  = 512;
constexpr int IN_ = 10;
constexpr int H_  = 32;
constexpr int NC_ = 9;
constexpr int XS_ = 12;    // x slot stride, floats (48 B, 16B-aligned slots)
constexpr int XB_ = 196;   // x buffer per batch, floats (16*12 + 4 pad)
constexpr int XT_ = 16;    // timesteps per chunk / x tile

typedef _Float16 h2v __attribute__((ext_vector_type(2)));
union U4H { uint4 u; h2v h[4]; };

__device__ __forceinline__ void cfence() { __asm__ volatile("" ::: "memory"); }

// Row-rotate by K within each DPP row of 16 lanes (VALU, no DS pipe).
template <int K>
__device__ __forceinline__ h2v rotk(h2v v) {
    int r = __builtin_amdgcn_update_dpp(
        0, __builtin_bit_cast(int, v), 0x120 + K, 0xF, 0xF, false);
    return __builtin_bit_cast(h2v, r);
}

// All-gather: d[k] = packed pair of row-lane (u + stp*k) & 15.
#define GATH(d, s)                                                        \
    d[0]  = (s);          d[1]  = rotk<1>(s);   d[2]  = rotk<2>(s);       \
    d[3]  = rotk<3>(s);   d[4]  = rotk<4>(s);   d[5]  = rotk<5>(s);       \
    d[6]  = rotk<6>(s);   d[7]  = rotk<7>(s);   d[8]  = rotk<8>(s);       \
    d[9]  = rotk<9>(s);   d[10] = rotk<10>(s);  d[11] = rotk<11>(s);      \
    d[12] = rotk<12>(s);  d[13] = rotk<13>(s);  d[14] = rotk<14>(s);      \
    d[15] = rotk<15>(s);

__global__ __launch_bounds__(128, 2) void gesture_rnn_kernel(
    const float* __restrict__ x,      // [B, T, IN]
    const float* __restrict__ W_ih0,  // [H, IN]
    const float* __restrict__ W_hh0,  // [H, H]
    const float* __restrict__ b_ih0,  // [H]
    const float* __restrict__ b_hh0,  // [H]
    const float* __restrict__ W_ih1,  // [H, H]
    const float* __restrict__ W_hh1,  // [H, H]
    const float* __restrict__ b_ih1,  // [H]
    const float* __restrict__ b_hh1,  // [H]
    const float* __restrict__ W_fc,   // [NC, H]
    const float* __restrict__ b_fc,   // [NC]
    float* __restrict__ out)          // [B, NC]
{
    const int tid  = threadIdx.x;     // 0..127
    const int wv   = tid >> 6;        // 0 = layer-0 producer, 1 = layer-1 consumer
    const int lane = tid & 63;
    const int bs   = lane >> 4;       // batch slot: 0..3
    const int u    = lane & 15;       // unit-pair index: owns units 2u, 2u+1
    const long b   = (long)blockIdx.x * 4 + bs;
    const int jA   = 2 * u, jB = 2 * u + 1;

    // ---- runtime direction probe for row_ror (direction-proof weights) ----
    const int pr  = __builtin_amdgcn_update_dpp(0, u, 0x121, 0xF, 0xF, false);
    const int stp = (pr - u) & 15;    // 1 or 15, uniform within each row

    // ---- per-wave weight preload ----
    float wxA[IN_], wxB[IN_];                  // A only
    h2v w0a[16], w0b[16];                      // A only (gather-permuted)
    h2v w1a[16], w1b[16];                      // B only (NATURAL order)
    h2v w2a[16], w2b[16];                      // B only (gather-permuted)
    float bias0A = 0.f, bias0B = 0.f, bias1A = 0.f, bias1B = 0.f;

    if (wv == 0) {
#pragma unroll
        for (int i = 0; i < IN_; ++i) {
            wxA[i] = W_ih0[jA * IN_ + i];
            wxB[i] = W_ih0[jB * IN_ + i];
        }
#pragma unroll
        for (int k = 0; k < 16; ++k) {
            const int s = (u + stp * k) & 15;
            w0a[k][0] = (_Float16)W_hh0[jA * H_ + 2 * s];
            w0a[k][1] = (_Float16)W_hh0[jA * H_ + 2 * s + 1];
            w0b[k][0] = (_Float16)W_hh0[jB * H_ + 2 * s];
            w0b[k][1] = (_Float16)W_hh0[jB * H_ + 2 * s + 1];
        }
        bias0A = b_ih0[jA] + b_hh0[jA];
        bias0B = b_ih0[jB] + b_hh0[jB];
    } else {
#pragma unroll
        for (int k = 0; k < 16; ++k) {
            // w1 multiplies natural-order h1 read from the ring: s = k.
            w1a[k][0] = (_Float16)W_ih1[jA * H_ + 2 * k];
            w1a[k][1] = (_Float16)W_ih1[jA * H_ + 2 * k + 1];
            w1b[k][0] = (_Float16)W_ih1[jB * H_ + 2 * k];
            w1b[k][1] = (_Float16)W_ih1[jB * H_ + 2 * k + 1];
            // w2 multiplies DPP-gathered h2: permuted.
            const int s = (u + stp * k) & 15;
            w2a[k][0] = (_Float16)W_hh1[jA * H_ + 2 * s];
            w2a[k][1] = (_Float16)W_hh1[jA * H_ + 2 * s + 1];
            w2b[k][0] = (_Float16)W_hh1[jB * H_ + 2 * s];
            w2b[k][1] = (_Float16)W_hh1[jB * H_ + 2 * s + 1];
        }
        bias1A = b_ih1[jA] + b_hh1[jA];
        bias1B = b_ih1[jB] + b_hh1[jB];
    }

    __shared__ __align__(16) float xtile[4][XB_];          // A-private x tile
    __shared__ __align__(16) unsigned int ring[2][XT_][4][16]; // h1 stream
    __shared__ __align__(4) _Float16 hfin[4][H_];          // h2[511] for FC

    // ---- x tile machinery (wave A): lane u owns timestep 16*ph + u ----
    const float* xg = x + ((size_t)b * T_ + u) * IN_;
    float xr[IN_];
    if (wv == 0) {
#pragma unroll
        for (int i = 0; i < IN_; i += 2) {                 // load tile 0
            float2 v = *(const float2*)(xg + i);
            xr[i] = v.x; xr[i + 1] = v.y;
        }
        xg += XT_ * IN_;
    }

    h2v p1; p1[0] = (_Float16)0.f; p1[1] = (_Float16)0.f;  // A: h1 pair
    h2v p2; p2[0] = (_Float16)0.f; p2[1] = (_Float16)0.f;  // B: h2 pair

#define STAGE(PREFETCH)                                                      \
    {                                                                        \
        float* dst_ = &xtile[bs][u * XS_];                                   \
        *(float4*)(dst_)     = make_float4(xr[0], xr[1], xr[2], xr[3]);      \
        *(float4*)(dst_ + 4) = make_float4(xr[4], xr[5], xr[6], xr[7]);      \
        *(float2*)(dst_ + 8) = make_float2(xr[8], xr[9]);                    \
        if (PREFETCH) {                                                      \
            _Pragma("unroll")                                                \
            for (int i_ = 0; i_ < IN_; i_ += 2) {                            \
                float2 v_ = *(const float2*)(xg + i_);                       \
                xr[i_] = v_.x; xr[i_ + 1] = v_.y;                            \
            }                                                                \
            xg += XT_ * IN_;                                                 \
        }                                                                    \
        cfence();                                                            \
    }

// Wave A step: h1[t] = relu(xproj + W_hh0 . h1[t-1]); stream pair to ring.
#define STEPA(RR, BUF)                                                       \
    {                                                                        \
        h2v h1h[16];                                                         \
        GATH(h1h, p1)                                                        \
        const float* xs_ = &xtile[bs][(RR) * XS_];                           \
        const float4 xv0_ = *(const float4*)(xs_);                           \
        const float4 xv1_ = *(const float4*)(xs_ + 4);                       \
        const float2 xv2_ = *(const float2*)(xs_ + 8);                       \
        const float xvv_[10] = {xv0_.x, xv0_.y, xv0_.z, xv0_.w,              \
                                xv1_.x, xv1_.y, xv1_.z, xv1_.w,              \
                                xv2_.x, xv2_.y};                             \
        float a1A0 = bias0A, a1A1 = 0.f, a1B0 = bias0B, a1B1 = 0.f;          \
        _Pragma("unroll")                                                    \
        for (int i_ = 0; i_ < IN_; i_ += 2) {                                \
            a1A0 = fmaf(wxA[i_],     xvv_[i_],     a1A0);                    \
            a1A1 = fmaf(wxA[i_ + 1], xvv_[i_ + 1], a1A1);                    \
            a1B0 = fmaf(wxB[i_],     xvv_[i_],     a1B0);                    \
            a1B1 = fmaf(wxB[i_ + 1], xvv_[i_ + 1], a1B1);                    \
        }                                                                    \
        _Pragma("unroll")                                                    \
        for (int k_ = 0; k_ < 8; ++k_) {                                     \
            a1A0 = __builtin_amdgcn_fdot2(w0a[k_],   h1h[k_],   a1A0, false);\
            a1A1 = __builtin_amdgcn_fdot2(w0a[k_+8], h1h[k_+8], a1A1, false);\
            a1B0 = __builtin_amdgcn_fdot2(w0b[k_],   h1h[k_],   a1B0, false);\
            a1B1 = __builtin_amdgcn_fdot2(w0b[k_+8], h1h[k_+8], a1B1, false);\
        }                                                                    \
        const float nh1A = fmaxf(a1A0 + a1A1, 0.f);                          \
        const float nh1B = fmaxf(a1B0 + a1B1, 0.f);                          \
        p1[0] = (_Float16)nh1A; p1[1] = (_Float16)nh1B;                      \
        ring[BUF][RR][bs][u] = __builtin_bit_cast(unsigned int, p1);         \
    }

// Wave B step: h2[t] = relu(bias1 + W_ih1 . h1[t] + W_hh1 . h2[t-1]).
#define STEPB(RR, BUF)                                                       \
    {                                                                        \
        h2v h2h[16];                                                         \
        GATH(h2h, p2)                                                        \
        h2v h1h[16];                                                         \
        const uint4* rp_ = (const uint4*)&ring[BUF][RR][bs][0];              \
        _Pragma("unroll")                                                    \
        for (int q_ = 0; q_ < 4; ++q_) {                                     \
            U4H a_; a_.u = rp_[q_];                                          \
            _Pragma("unroll")                                                \
            for (int r_ = 0; r_ < 4; ++r_) h1h[4 * q_ + r_] = a_.h[r_];      \
        }                                                                    \
        float a2A0 = bias1A, a2A1 = 0.f, a2A2 = 0.f, a2A3 = 0.f;             \
        float a2B0 = bias1B, a2B1 = 0.f, a2B2 = 0.f, a2B3 = 0.f;             \
        _Pragma("unroll")                                                    \
        for (int k_ = 0; k_ < 8; ++k_) {                                     \
            a2A0 = __builtin_amdgcn_fdot2(w1a[k_],   h1h[k_],   a2A0, false);\
            a2A1 = __builtin_amdgcn_fdot2(w1a[k_+8], h1h[k_+8], a2A1, false);\
            a2A2 = __builtin_amdgcn_fdot2(w2a[k_],   h2h[k_],   a2A2, false);\
            a2A3 = __builtin_amdgcn_fdot2(w2a[k_+8], h2h[k_+8], a2A3, false);\
            a2B0 = __builtin_amdgcn_fdot2(w1b[k_],   h1h[k_],   a2B0, false);\
            a2B1 = __builtin_amdgcn_fdot2(w1b[k_+8], h1h[k_+8], a2B1, false);\
            a2B2 = __builtin_amdgcn_fdot2(w2b[k_],   h2h[k_],   a2B2, false);\
            a2B3 = __builtin_amdgcn_fdot2(w2b[k_+8], h2h[k_+8], a2B3, false);\
        }                                                                    \
        const float nh2A = fmaxf((a2A0 + a2A1) + (a2A2 + a2A3), 0.f);        \
        const float nh2B = fmaxf((a2B0 + a2B1) + (a2B2 + a2B3), 0.f);        \
        p2[0] = (_Float16)nh2A; p2[1] = (_Float16)nh2B;                      \
    }

    // ---- phase loop: A produces chunk ph (ph<32); B consumes chunk ph-1 ----
#pragma unroll 1
    for (int ph = 0; ph < 33; ++ph) {
        if (wv == 0) {
            if (ph < 32) {
                STAGE(ph < 31);
                const int buf = ph & 1;
#pragma unroll 4
                for (int r = 0; r < 16; ++r) STEPA(r, buf);
            }
        } else {
            if (ph >= 1) {
                const int buf = (ph - 1) & 1;
#pragma unroll 4
                for (int r = 0; r < 16; ++r) STEPB(r, buf);
            }
        }
        // LGKMCNT-only drain (no vmcnt!) + raw barrier, fenced both sides.
        __asm__ volatile("s_waitcnt lgkmcnt(0)" ::: "memory");
        __builtin_amdgcn_s_barrier();
        __asm__ volatile("" ::: "memory");
    }

    // ---- FC head (wave B): p2 = h2[511] pairs ----
    if (wv == 1) {
        *(h2v*)&hfin[bs][2 * u] = p2;
        cfence();
        if (u < NC_) {
            float acc = b_fc[u];
#pragma unroll
            for (int k = 0; k < H_; ++k)
                acc = fmaf(W_fc[u * H_ + k], (float)hfin[bs][k], acc);
            out[b * NC_ + u] = acc;
        }
    }
#undef STAGE
#undef STEPA
#undef STEPB
}

extern "C" void kernel_launch(void* const* d_in, const int* in_sizes, int n_in,
                              void* d_out, int out_size, void* d_ws, size_t ws_size,
                              hipStream_t stream) {
    const float* x     = (const float*)d_in[0];
    const float* W_ih0 = (const float*)d_in[1];
    const float* W_hh0 = (const float*)d_in[2];
    const float* b_ih0 = (const float*)d_in[3];
    const float* b_hh0 = (const float*)d_in[4];
    const float* W_ih1 = (const float*)d_in[5];
    const float* W_hh1 = (const float*)d_in[6];
    const float* b_ih1 = (const float*)d_in[7];
    const float* b_hh1 = (const float*)d_in[8];
    const float* W_fc  = (const float*)d_in[9];
    const float* b_fc  = (const float*)d_in[10];
    float* out = (float*)d_out;

    const int B = in_sizes[0] / (T_ * IN_);   // 4096
    gesture_rnn_kernel<<<dim3(B / 4), dim3(128), 0, stream>>>(
        x, W_ih0, W_hh0, b_ih0, b_hh0, W_ih1, W_hh1, b_ih1, b_hh1,
        W_fc, b_fc, out);
}

// Round 4
// 301.222 us; speedup vs baseline: 1.0306x; 1.0306x over previous
//
#include <hip/hip_runtime.h>

// GestureRNN v12: MFMA recurrence with layout-closed weight conjugation.
// B=4096, T=512, IN=10, H=32, NCLS=9.
//
// v11 post-mortem: 2 waves/SIMD (occ 11.6->19.9) changed nothing (215->223us,
// VALUBusy 80-82% both) => VALU-THROUGHPUT-bound at ~5 cyc/inst effective
// (~830 busy cyc/step/SIMD for ~165 inst). fdot2 on the VALU pipe is the
// bottleneck; no wave count or instruction diet fixes that. v12 moves the
// 3x (32x32)@h GEMVs to the matrix pipe: 16 batches = MFMA N-dim, 6x
// mfma_f32_16x16x32_f16 per step. KEY: with k-order K(k)=16*((k>>2)&1)+
// 4*(k>>3)+(k&3) baked into all recurrent A-fragments, the C/D fragment
// (lane(g,c) regs = units {4g..4g+3} u {16+4g..+3}) IS the next B-fragment
// lane-locally: relu + 8 cvt, ZERO cross-lane ops between steps.
// xproj: per-16-step chunk via MFMA with f32-accurate split
// (Whi@xhi + Whi@xlo + Wlo@xhi), biases folded into MFMA C-init.
// Single wave/block (in-order DS pipe -> no barriers), 256 blocks.

constexpr int T_  = 512;
constexpr int IN_ = 10;
constexpr int H_  = 32;
constexpr int NC_ = 9;
constexpr int CT_ = 16;        // timesteps per chunk
constexpr int NCH = T_ / CT_;  // 32 chunks
constexpr int XP_ = 20;        // padded floats per (slot,lane) in xlds

typedef _Float16 f16x8 __attribute__((ext_vector_type(8)));
typedef float    f32x4 __attribute__((ext_vector_type(4)));

__device__ __forceinline__ void cfence() { __asm__ volatile("" ::: "memory"); }

__device__ __forceinline__ f32x4 MFMA(f16x8 a, f16x8 b, f32x4 c) {
    return __builtin_amdgcn_mfma_f32_16x16x32_f16(a, b, c, 0, 0, 0);
}

__global__ __launch_bounds__(64, 1) void gesture_rnn_kernel(
    const float* __restrict__ x,      // [B, T, IN]
    const float* __restrict__ W_ih0,  // [H, IN]
    const float* __restrict__ W_hh0,  // [H, H]
    const float* __restrict__ b_ih0,  // [H]
    const float* __restrict__ b_hh0,  // [H]
    const float* __restrict__ W_ih1,  // [H, H]
    const float* __restrict__ W_hh1,  // [H, H]
    const float* __restrict__ b_ih1,  // [H]
    const float* __restrict__ b_hh1,  // [H]
    const float* __restrict__ W_fc,   // [NC, H]
    const float* __restrict__ b_fc,   // [NC]
    float* __restrict__ out)          // [B, NC]
{
    const int lane = threadIdx.x;     // 0..63
    const int c    = lane & 15;       // batch slot (B/C col, A row)
    const int g    = lane >> 4;       // k-group (A/B), C row-group
    const long b   = (long)blockIdx.x * 16 + c;

    // ---- A-fragments. Lane l: row = l&15, k = (l>>4)*8 + j.
    //      Recurrent matrices use k-order K(k); xproj uses natural k. ----
    f16x8 ah0[2], ai1[2], ah1[2], axh[2], axl[2];
#pragma unroll
    for (int Tt = 0; Tt < 2; ++Tt) {
#pragma unroll
        for (int j = 0; j < 8; ++j) {
            const int k   = 8 * g + j;
            const int kp  = 16 * ((k >> 2) & 1) + 4 * (k >> 3) + (k & 3);
            const int row = 16 * Tt + c;
            ah0[Tt][j] = (_Float16)W_hh0[row * H_ + kp];
            ai1[Tt][j] = (_Float16)W_ih1[row * H_ + kp];
            ah1[Tt][j] = (_Float16)W_hh1[row * H_ + kp];
            const float wx = (k < IN_) ? W_ih0[row * IN_ + k] : 0.f;
            const _Float16 wh = (_Float16)wx;
            axh[Tt][j] = wh;
            axl[Tt][j] = (_Float16)(wx - (float)wh);   // residual for f32 accuracy
        }
    }
    // ---- bias C-inits (C layout: lane(g,c) reg r = unit 16T+4g+r) ----
    f32x4 b0i[2], b1i[2];
#pragma unroll
    for (int Tt = 0; Tt < 2; ++Tt)
#pragma unroll
        for (int r = 0; r < 4; ++r) {
            const int uu = 16 * Tt + 4 * g + r;
            b0i[Tt][r] = b_ih0[uu] + b_hh0[uu];
            b1i[Tt][r] = b_ih1[uu] + b_hh1[uu];
        }

    __shared__ float xlds[4 * 64 * XP_];     // [slot][lane][20] x staging
    __shared__ _Float16 hfin[16][H_];        // final h2 for FC head

    // ---- x staging: lane(g,c) owns timesteps 4g+s (s=0..3) of batch b ----
    float xr[4][IN_];
    const float* xg = x + ((size_t)b * T_ + 4 * g) * IN_;
#pragma unroll
    for (int s = 0; s < 4; ++s)
#pragma unroll
        for (int i = 0; i < IN_; i += 2) {
            const float2 v = *(const float2*)(xg + s * IN_ + i);
            xr[s][i] = v.x; xr[s][i + 1] = v.y;
        }
    xg += CT_ * IN_;

    f16x8 h1f, h2f;
#pragma unroll
    for (int j = 0; j < 8; ++j) { h1f[j] = (_Float16)0.f; h2f[j] = (_Float16)0.f; }

    f32x4 xp0[CT_], xp1[CT_];

#pragma unroll 1
    for (int n = 0; n < NCH; ++n) {
        // ---- dump chunk n x regs to LDS (compiler inserts the vmcnt wait) ----
#pragma unroll
        for (int s = 0; s < 4; ++s) {
            float* dst = &xlds[(s * 64 + lane) * XP_];
            *(float4*)(dst)     = make_float4(xr[s][0], xr[s][1], xr[s][2], xr[s][3]);
            *(float4*)(dst + 4) = make_float4(xr[s][4], xr[s][5], xr[s][6], xr[s][7]);
            *(float2*)(dst + 8) = make_float2(xr[s][8], xr[s][9]);
        }
        // ---- prefetch chunk n+1 (in flight across the whole chunk) ----
        if (n + 1 < NCH) {
#pragma unroll
            for (int s = 0; s < 4; ++s)
#pragma unroll
                for (int i = 0; i < IN_; i += 2) {
                    const float2 v = *(const float2*)(xg + s * IN_ + i);
                    xr[s][i] = v.x; xr[s][i + 1] = v.y;
                }
            xg += CT_ * IN_;
        }
        cfence();

        // ---- xproj phase: xp[t] = W_ih0 @ x[t] + b0, f32-accurate split ----
#pragma unroll
        for (int t = 0; t < CT_; ++t) {
            const float* rp = &xlds[((t & 3) * 64 + (t >> 2) * 16 + c) * XP_];
            f16x8 bxh, bxl;
#pragma unroll
            for (int j = 0; j < 8; ++j) { bxh[j] = (_Float16)0.f; bxl[j] = (_Float16)0.f; }
            if (g == 0) {
                const float4 v0 = *(const float4*)rp;
                const float4 v1 = *(const float4*)(rp + 4);
                const float xv[8] = {v0.x, v0.y, v0.z, v0.w, v1.x, v1.y, v1.z, v1.w};
#pragma unroll
                for (int j = 0; j < 8; ++j) {
                    const _Float16 hh = (_Float16)xv[j];
                    bxh[j] = hh; bxl[j] = (_Float16)(xv[j] - (float)hh);
                }
            } else if (g == 1) {
                const float2 v2 = *(const float2*)(rp + 8);
                const _Float16 ha = (_Float16)v2.x;
                bxh[0] = ha; bxl[0] = (_Float16)(v2.x - (float)ha);
                const _Float16 hb = (_Float16)v2.y;
                bxh[1] = hb; bxl[1] = (_Float16)(v2.y - (float)hb);
            }
            f32x4 p0 = MFMA(axh[0], bxh, b0i[0]);
            p0 = MFMA(axh[0], bxl, p0);
            p0 = MFMA(axl[0], bxh, p0);
            f32x4 p1 = MFMA(axh[1], bxh, b0i[1]);
            p1 = MFMA(axh[1], bxl, p1);
            p1 = MFMA(axl[1], bxh, p1);
            xp0[t] = p0; xp1[t] = p1;
        }

        // ---- recurrence: 16 steps, pure register + matrix pipe ----
#pragma unroll
        for (int t = 0; t < CT_; ++t) {
            const f32x4 c0 = MFMA(ah0[0], h1f, xp0[t]);
            const f32x4 c1 = MFMA(ah0[1], h1f, xp1[t]);
            f16x8 nh1;
#pragma unroll
            for (int r = 0; r < 4; ++r) nh1[r]     = (_Float16)fmaxf(c0[r], 0.f);
#pragma unroll
            for (int r = 0; r < 4; ++r) nh1[4 + r] = (_Float16)fmaxf(c1[r], 0.f);
            f32x4 d0 = MFMA(ai1[0], nh1, b1i[0]);
            d0 = MFMA(ah1[0], h2f, d0);
            f32x4 d1 = MFMA(ai1[1], nh1, b1i[1]);
            d1 = MFMA(ah1[1], h2f, d1);
            f16x8 nh2;
#pragma unroll
            for (int r = 0; r < 4; ++r) nh2[r]     = (_Float16)fmaxf(d0[r], 0.f);
#pragma unroll
            for (int r = 0; r < 4; ++r) nh2[4 + r] = (_Float16)fmaxf(d1[r], 0.f);
            h1f = nh1; h2f = nh2;
        }
    }

    // ---- FC head: h2f C-layout -> hfin[c][unit], then 2-3 classes/lane ----
#pragma unroll
    for (int r = 0; r < 4; ++r) {
        hfin[c][4 * g + r]      = h2f[r];
        hfin[c][16 + 4 * g + r] = h2f[4 + r];
    }
    cfence();   // single-wave in-order DS pipe: writes precede reads
    {
        float acc0 = b_fc[g];
        float acc1 = b_fc[g + 4];
        float acc2 = (g == 0) ? b_fc[8] : 0.f;
#pragma unroll
        for (int k = 0; k < H_; ++k) {
            const float hv = (float)hfin[c][k];
            acc0 = fmaf(W_fc[g * H_ + k], hv, acc0);
            acc1 = fmaf(W_fc[(g + 4) * H_ + k], hv, acc1);
            if (g == 0) acc2 = fmaf(W_fc[8 * H_ + k], hv, acc2);
        }
        out[b * NC_ + g]     = acc0;
        out[b * NC_ + g + 4] = acc1;
        if (g == 0) out[b * NC_ + 8] = acc2;
    }
}

extern "C" void kernel_launch(void* const* d_in, const int* in_sizes, int n_in,
                              void* d_out, int out_size, void* d_ws, size_t ws_size,
                              hipStream_t stream) {
    const float* x     = (const float*)d_in[0];
    const float* W_ih0 = (const float*)d_in[1];
    const float* W_hh0 = (const float*)d_in[2];
    const float* b_ih0 = (const float*)d_in[3];
    const float* b_hh0 = (const float*)d_in[4];
    const float* W_ih1 = (const float*)d_in[5];
    const float* W_hh1 = (const float*)d_in[6];
    const float* b_ih1 = (const float*)d_in[7];
    const float* b_hh1 = (const float*)d_in[8];
    const float* W_fc  = (const float*)d_in[9];
    const float* b_fc  = (const float*)d_in[10];
    float* out = (float*)d_out;

    const int B = in_sizes[0] / (T_ * IN_);   // 4096
    gesture_rnn_kernel<<<dim3(B / 16), dim3(64), 0, stream>>>(
        x, W_ih0, W_hh0, b_ih0, b_hh0, W_ih1, W_hh1, b_ih1, b_hh1,
        W_fc, b_fc, out);
}